// Round 4
// baseline (371.118 us; speedup 1.0000x reference)
//
#include <hip/hip_runtime.h>

// Sparse 3D conv (Cin=1, Cout=16), rulebook form:
//   out[out_idx[m], c] += feats[in_idx[m]] * weight[k_idx[m], c]
//
// k_idx sorted (27 segments); out_idx strictly increasing within each
// segment -> per output tile [o0,o0+TILE) each segment contributes one
// contiguous run. Runs for ALL tiles are precomputed by a parallel
// bounds kernel (hi of tile t == lo of tile t+1). Main kernel: per wave,
// gather 64 entries at a time (coalesced index loads + 64 independent
// feats gathers in flight), broadcast (f, row) via __shfl to 16-lane
// channel groups, accumulate with ds_add_f32 into a 512x16 LDS tile,
// write the tile once (coalesced float4). No global atomics, no memset.

#define TILE 512
#define NK 27

__device__ __forceinline__ int lower_bound_i32(const int* __restrict__ a,
                                               int lo, int hi, int val) {
    while (lo < hi) {
        int mid = (lo + hi) >> 1;
        if (a[mid] < val) lo = mid + 1; else hi = mid;
    }
    return lo;
}

// ks[t] = first m with k_idx[m] >= t; ks[27] = M.
__global__ void k_bounds_kernel(const int* __restrict__ k_idx, int M,
                                int* __restrict__ ks) {
    int t = threadIdx.x;
    if (t <= NK) ks[t] = lower_bound_i32(k_idx, 0, M, t);
}

// bounds[t*NK + k] = first m in segment k with out_idx[m] >= min(t*TILE, n_out)
// for t in [0, num_tiles]. One thread per (t, k): fully parallel searches.
__global__ void tile_bounds_kernel(const int* __restrict__ out_idx,
                                   const int* __restrict__ ks,
                                   int* __restrict__ bounds,
                                   int num_tiles, int n_out) {
    int idx = blockIdx.x * blockDim.x + threadIdx.x;
    int total = (num_tiles + 1) * NK;
    if (idx >= total) return;
    int t = idx / NK;
    int k = idx - t * NK;
    int q = t * TILE;
    if (q > n_out) q = n_out;
    bounds[idx] = lower_bound_i32(out_idx, ks[k], ks[k + 1], q);
}

__global__ __launch_bounds__(256, 4) void sparse_conv_tiled(
    const float* __restrict__ feats,
    const float* __restrict__ weight,
    const int* __restrict__ in_idx,
    const int* __restrict__ out_idx,
    const int* __restrict__ ks,
    const int* __restrict__ bounds,   // t-major [num_tiles+1][NK], or null
    float* __restrict__ out,
    int n_out) {
    __shared__ float tile[TILE * 16];   // 32 KB -> 4 blocks/CU
    __shared__ int lo_s[NK], hi_s[NK];

    const int tid = threadIdx.x;
    const int tblk = blockIdx.x;
    const int o0 = tblk * TILE;
    const int rows = min(TILE, n_out - o0);

    // Zero the LDS tile (vectorized).
    float4* t4 = (float4*)tile;
    for (int i = tid; i < TILE * 4; i += 256)
        t4[i] = make_float4(0.f, 0.f, 0.f, 0.f);

    if (bounds) {
        if (tid < NK)                     lo_s[tid]      = bounds[tblk * NK + tid];
        else if (tid >= 32 && tid < 32 + NK) hi_s[tid - 32] = bounds[(tblk + 1) * NK + (tid - 32)];
    } else {
        if (tid < NK)
            lo_s[tid] = lower_bound_i32(out_idx, ks[tid], ks[tid + 1], o0);
        else if (tid >= 64 && tid < 64 + NK) {
            int k = tid - 64;
            hi_s[k] = lower_bound_i32(out_idx, ks[k], ks[k + 1], o0 + rows);
        }
    }
    __syncthreads();

    const int wave = tid >> 6;
    const int lane = tid & 63;
    const int c = lane & 15;            // this lane's channel
    const int g = lane >> 4;            // this lane's entry-subgroup (0..3)

    // Wave-uniform k; 64-entry batched gather then shfl-distribute.
    for (int k = wave; k < NK; k += 4) {
        const int lo = lo_s[k];
        const int hi = hi_s[k];
        if (lo >= hi) continue;
        const float w = weight[k * 16 + c];
        for (int base = lo; base < hi; base += 64) {
            int m = base + lane;
            int mc = m < hi ? m : hi - 1;       // clamp (stays in-tile)
            int i = in_idx[mc];                  // coalesced
            int o = out_idx[mc];                 // coalesced
            float f = feats[i];                  // 64 independent gathers
            if (m >= hi) f = 0.0f;               // tail adds zero
            int abase = (o - o0) * 16;

            int cnt = hi - base; if (cnt > 64) cnt = 64;
            int tmax = (cnt + 3) >> 2;           // entry groups of 4
            for (int t = 0; t < tmax; ++t) {
                int src = t * 4 + g;
                float fe = __shfl(f, src);
                int   ae = __shfl(abase, src);
                atomicAdd(&tile[ae + c], fe * w);   // ds_add_f32
            }
        }
    }
    __syncthreads();

    // Coalesced tile writeback (every row written -> no memset needed).
    float4* out4 = (float4*)(out + (size_t)o0 * 16);
    for (int i = tid; i < rows * 4; i += 256)
        out4[i] = t4[i];
}

extern "C" void kernel_launch(void* const* d_in, const int* in_sizes, int n_in,
                              void* d_out, int out_size, void* d_ws, size_t ws_size,
                              hipStream_t stream) {
    const float* feats   = (const float*)d_in[0];
    const float* weight  = (const float*)d_in[1];
    const int*   in_idx  = (const int*)d_in[2];
    const int*   out_idx = (const int*)d_in[3];
    const int*   k_idx   = (const int*)d_in[4];
    float*       out     = (float*)d_out;

    const int M = in_sizes[2];          // rulebook length
    const int n_out = out_size / 16;    // output rows
    const int num_tiles = (n_out + TILE - 1) / TILE;

    int* ks = (int*)d_ws;               // 32 ints
    int* bounds = ks + 32;              // (num_tiles+1)*NK ints
    const size_t need = (32 + (size_t)(num_tiles + 1) * NK) * sizeof(int);
    const bool use_bounds = ws_size >= need;

    k_bounds_kernel<<<1, 32, 0, stream>>>(k_idx, M, ks);

    if (use_bounds) {
        int total = (num_tiles + 1) * NK;
        tile_bounds_kernel<<<(total + 255) / 256, 256, 0, stream>>>(
            out_idx, ks, bounds, num_tiles, n_out);
    }

    sparse_conv_tiled<<<num_tiles, 256, 0, stream>>>(
        feats, weight, in_idx, out_idx, ks,
        use_bounds ? bounds : (const int*)nullptr, out, n_out);
}